// Round 19
// baseline (548.075 us; speedup 1.0000x reference)
//
#include <hip/hip_runtime.h>
#include <cstddef>
#include <cstdint>

constexpr int N_NODES = 8192;
constexpr int E_EDGES = 262144;
constexpr int ET = E_EDGES + N_NODES;   // + self loops
constexpr int IN_DIM = 256;
constexpr int HID = 128;
constexpr int SLOTS = 128;              // per-dst bucket capacity (deg~Poisson(33))
constexpr int GRID = 512;               // 2 blocks/CU x 256 CUs -> all co-resident
constexpr float NEG_ATT = 0.2f;
constexpr float NEG_ACT = 0.02f;

typedef __attribute__((ext_vector_type(8))) short bf16x8;
typedef __attribute__((ext_vector_type(4))) float f32x4;

__device__ inline float lrelu(float v, float s) { return v >= 0.f ? v : s * v; }

#define GLD_LDS16(gaddr, laddr) \
    __builtin_amdgcn_global_load_lds( \
        (const __attribute__((address_space(1))) void*)(gaddr), \
        (__attribute__((address_space(3))) void*)(laddr), 16, 0, 0)

// ---- manual grid barrier: release fence -> arrive -> spin -> acquire fence ----
// Bounded spin: if co-residency ever fails, we produce a visible wrong answer
// instead of a hang. Counters are per-phase, zeroed by zero_k each launch.
__device__ inline void grid_barrier(int* bar, int nblk) {
    __threadfence();                 // release: all prior global writes visible
    __syncthreads();
    if (threadIdx.x == 0) {
        atomicAdd(bar, 1);           // device-scope
        int spins = 0;
        while (atomicAdd(bar, 0) < nblk && spins < (1 << 21)) {
            __builtin_amdgcn_s_sleep(2);
            ++spins;
        }
    }
    __syncthreads();
    __threadfence();                 // acquire: don't read stale lines
}

__global__ __launch_bounds__(1024) void zero_k(int* __restrict__ cnt,
                                               int* __restrict__ bar) {
    int i = blockIdx.x * 1024 + threadIdx.x;
    if (i < N_NODES) cnt[i] = 0;
    if (i < 8) bar[i] = 0;
}

struct MegaArgs {
    const float* x; const int* ei;
    const float* W1; const float* a1s; const float* a1d; const float* b1;
    const float* W2; const float* a2s; const float* a2d; const float* b2;
    float* h; float* act; int* cnt; int* csr;
    float* asrc; float* adst; unsigned short* hi; int* bar;
};

// ---- linear unit: 8 nodes, 256 threads (two 128-thread halves x 4 nodes) ----
__device__ void linear_unit(const float* __restrict__ x, const float* __restrict__ W,
                            const float* __restrict__ a_s, const float* __restrict__ a_d,
                            float* __restrict__ h, float* __restrict__ asrc,
                            float* __restrict__ adst, int in_dim,
                            float (*xs)[256], float (*red)[4][2], int t, int u)
{
    const int n0 = u * 8;
    const int c = t & 127, hb = t >> 7, w = t >> 6, lane = t & 63;
    for (int n = 0; n < 8; ++n)
        for (int i = t; i < in_dim; i += 256) xs[n][i] = x[(size_t)(n0 + n) * in_dim + i];
    __syncthreads();
    float acc[4] = {0.f, 0.f, 0.f, 0.f};
    const float* Wc = W + c;
    for (int i4 = 0; i4 < in_dim / 4; ++i4) {
        float4 xv[4];
        #pragma unroll
        for (int n = 0; n < 4; ++n) xv[n] = *(const float4*)&xs[hb * 4 + n][i4 * 4];
        float w0 = Wc[(i4 * 4 + 0) * HID];
        float w1 = Wc[(i4 * 4 + 1) * HID];
        float w2 = Wc[(i4 * 4 + 2) * HID];
        float w3 = Wc[(i4 * 4 + 3) * HID];
        #pragma unroll
        for (int n = 0; n < 4; ++n) {
            acc[n] = fmaf(xv[n].x, w0, acc[n]);
            acc[n] = fmaf(xv[n].y, w1, acc[n]);
            acc[n] = fmaf(xv[n].z, w2, acc[n]);
            acc[n] = fmaf(xv[n].w, w3, acc[n]);
        }
    }
    #pragma unroll
    for (int n = 0; n < 4; ++n) h[(size_t)(n0 + hb * 4 + n) * HID + c] = acc[n];
    const float As = a_s[c], Ad = a_d[c];
    #pragma unroll
    for (int n = 0; n < 4; ++n) {
        float vs = acc[n] * As, vd = acc[n] * Ad;
        #pragma unroll
        for (int off = 32; off; off >>= 1) {
            vs += __shfl_down(vs, off, 64);
            vd += __shfl_down(vd, off, 64);
        }
        if (lane == 0) { red[w][n][0] = vs; red[w][n][1] = vd; }
    }
    __syncthreads();
    if (t < 8) {
        int hb2 = t >> 2, n = t & 3;
        asrc[n0 + hb2 * 4 + n] = red[hb2 * 2][n][0] + red[hb2 * 2 + 1][n][0];
        adst[n0 + hb2 * 4 + n] = red[hb2 * 2][n][1] + red[hb2 * 2 + 1][n][1];
    }
}

// ---- aggregate: one wave per dst (round-16 math verbatim) ----
template<int EMIT>
__device__ void agg_unit(int d, const int* __restrict__ cnt, const int* __restrict__ csr,
                         const float* __restrict__ asrc, const float* __restrict__ adst,
                         const float* __restrict__ h, const float* __restrict__ bias,
                         float* __restrict__ out, unsigned short* __restrict__ hi,
                         float* wbuf, int* sbuf, int lane)
{
    int deg = cnt[d]; if (deg > SLOTS) deg = SLOTS;
    const float ad = adst[d];
    const int base = d * SLOTS;

    float sm = 0.f;
    for (int j = lane; j < deg; j += 64) {
        int s = csr[base + j];
        float e = asrc[s] + ad; e = e >= 0.f ? e : NEG_ATT * e;
        float ww = __expf(e);
        wbuf[j] = ww; sbuf[j] = s;
        sm += ww;
    }
    #pragma unroll
    for (int off = 32; off; off >>= 1) sm += __shfl_xor(sm, off, 64);
    const float inv = 1.f / sm;

    float ax = 0.f, ay = 0.f;
    #pragma unroll 4
    for (int j = 0; j < deg; ++j) {
        float ww = wbuf[j];
        int   s  = sbuf[j];
        const float2 hv = *(const float2*)(h + ((size_t)s << 7) + lane * 2);
        ax = fmaf(ww, hv.x, ax);
        ay = fmaf(ww, hv.y, ay);
    }
    const float2 bv = *(const float2*)(bias + lane * 2);
    float vx = lrelu(fmaf(ax, inv, bv.x), NEG_ACT);
    float vy = lrelu(fmaf(ay, inv, bv.y), NEG_ACT);

    if (EMIT) {
        uint32_t ux = __float_as_uint(vx);
        uint32_t rhx = (ux + 0x7FFFu + ((ux >> 16) & 1u)) & 0xFFFF0000u;   // RNE
        uint32_t uy = __float_as_uint(vy);
        uint32_t rhy = (uy + 0x7FFFu + ((uy >> 16) & 1u)) & 0xFFFF0000u;
        *(uint32_t*)(hi + ((size_t)d << 7) + lane * 2) = (rhx >> 16) | (rhy & 0xFFFF0000u);
    } else {
        *(float2*)(out + ((size_t)d << 7) + lane * 2) = make_float2(vx, vy);
    }
}

// ---- persistent mega kernel: linear1 | append | agg1 | linear2 | agg2 ----
__global__ __launch_bounds__(256, 2) void gat_mega_k(MegaArgs A)
{
    __shared__ __align__(16) float xs[8][256];
    __shared__ float red[4][4][2];
    __shared__ float wbuf[4][SLOTS];
    __shared__ int   sbuf[4][SLOTS];

    const int t = threadIdx.x;
    const int bid = blockIdx.x;
    const int lane = t & 63, wv = t >> 6;

    // P1: layer-1 linear + logits
    for (int u = bid; u < N_NODES / 8; u += GRID)
        linear_unit(A.x, A.W1, A.a1s, A.a1d, A.h, A.asrc, A.adst, IN_DIM, xs, red, t, u);
    grid_barrier(&A.bar[0], GRID);

    // P2: bucketed adjacency append
    for (int i = bid * 256 + t; i < ET; i += GRID * 256) {
        int s, d;
        if (i < E_EDGES) { s = A.ei[i]; d = A.ei[E_EDGES + i]; }
        else             { s = i - E_EDGES; d = s; }
        int pos = atomicAdd(&A.cnt[d], 1);
        if (pos < SLOTS) A.csr[d * SLOTS + pos] = s;
    }
    grid_barrier(&A.bar[1], GRID);

    // P3: layer-1 aggregate -> act
    for (int d = bid * 4 + wv; d < N_NODES; d += GRID * 4)
        agg_unit<0>(d, A.cnt, A.csr, A.asrc, A.adst, A.h, A.b1, A.act, nullptr,
                    wbuf[wv], sbuf[wv], lane);
    grid_barrier(&A.bar[2], GRID);

    // P4: layer-2 linear + logits (h, asrc, adst overwritten)
    for (int u = bid; u < N_NODES / 8; u += GRID)
        linear_unit(A.act, A.W2, A.a2s, A.a2d, A.h, A.asrc, A.adst, HID, xs, red, t, u);
    grid_barrier(&A.bar[3], GRID);

    // P5: layer-2 aggregate -> bf16 hi
    for (int d = bid * 4 + wv; d < N_NODES; d += GRID * 4)
        agg_unit<1>(d, A.cnt, A.csr, A.asrc, A.adst, A.h, A.b2, nullptr, A.hi,
                    wbuf[wv], sbuf[wv], lane);
}

// ---------------- C = A A^T, hh-only bf16 MFMA, symmetric ----------------
// ROUND-16 VERBATIM: BK=64 2-panel staging, halved epilogue (8 KB/wave T),
// 32 KB LDS + __launch_bounds__(256,4) -> 4 blocks/CU.
__global__ __launch_bounds__(256, 4) void aat_mfma_k(
    const unsigned short* __restrict__ hi, float* __restrict__ C)
{
    __shared__ __align__(16) unsigned char smraw[32768];
    unsigned short* sm = (unsigned short*)smraw;   // 2 panels of 128x64 bf16 (32 KB)
    const int t = threadIdx.x;
    const int lane = t & 63, wv = t >> 6;

    int b = blockIdx.x;
    int ti, tj;
    if (b < 2016) {                      // strict lower: ti in [1,63], tj < ti
        ti = (int)((__builtin_sqrtf(8.f * b + 1.f) + 1.f) * 0.5f);
        while (ti * (ti - 1) / 2 > b) --ti;
        while ((ti + 1) * ti / 2 <= b) ++ti;
        tj = b - ti * (ti - 1) / 2;
    } else {                             // diagonal (half work) scheduled last
        ti = b - 2016; tj = ti;
    }
    const int bi = ti * 128, bj = tj * 128;

    const int wi0 = (wv >> 1) * 64, wj0 = (wv & 1) * 64;
    const int lr = lane & 15, g = lane >> 4;

    f32x4 acc[4][4] = {};

    const int gbase[2] = { bi, bj };

    for (int ks = 0; ks < 2; ++ks) {
        if (ks) __syncthreads();
        #pragma unroll
        for (int arr = 0; arr < 2; ++arr) {
            #pragma unroll
            for (int call = 0; call < 4; ++call) {
                int r0 = wv * 32 + call * 8;            // wave-uniform
                int r = r0 + (lane >> 3);
                int chunk = (lane & 7) ^ (r & 7);
                const unsigned short* gp = hi
                    + (size_t)(gbase[arr] + r) * HID + ks * 64 + chunk * 8;
                unsigned short* lp = sm + arr * 8192 + r0 * 64;  // uniform base
                GLD_LDS16(gp, lp);
            }
        }
        __syncthreads();   // drains vmcnt

        #pragma unroll
        for (int kw = 0; kw < 2; ++kw) {
            bf16x8 ah[4], bh[4];
            #pragma unroll
            for (int f = 0; f < 4; ++f) {
                int rA = wi0 + f * 16 + lr;
                int csA = (kw * 4 + g) ^ (rA & 7);
                ah[f] = *(const bf16x8*)(sm + 0 * 8192 + rA * 64 + csA * 8);
                int rB = wj0 + f * 16 + lr;
                int csB = (kw * 4 + g) ^ (rB & 7);
                bh[f] = *(const bf16x8*)(sm + 1 * 8192 + rB * 64 + csB * 8);
            }
            #pragma unroll
            for (int fi = 0; fi < 4; ++fi)
                #pragma unroll
                for (int fj = 0; fj < 4; ++fj)
                    acc[fi][fj] = __builtin_amdgcn_mfma_f32_16x16x32_bf16(ah[fi], bh[fj], acc[fi][fj], 0, 0, 0);
        }
    }

    __syncthreads();                       // panels dead for all waves
    float* T = (float*)smraw + wv * 2048;  // per-wave 32x64 f32 (8 KB), XOR swizzle

    // ---- direct tile, two 32-row halves
    #pragma unroll
    for (int hh = 0; hh < 2; ++hh) {
        #pragma unroll
        for (int fi = 2 * hh; fi < 2 * hh + 2; ++fi)
            #pragma unroll
            for (int fj = 0; fj < 4; ++fj)
                #pragma unroll
                for (int q = 0; q < 4; ++q) {
                    int row = fi * 16 + g * 4 + q - 32 * hh;   // 0..31
                    int chunk = (fj * 4 + (lr >> 2)) ^ (row & 15);
                    T[row * 64 + chunk * 4 + (lr & 3)] = acc[fi][fj][q];
                }
        #pragma unroll
        for (int it = 0; it < 8; ++it) {
            int row = it * 4 + g;
            f32x4 v = *(const f32x4*)(T + row * 64 + ((lr ^ (row & 15)) << 2));
            *(f32x4*)(C + (size_t)(bi + wi0 + 32 * hh + row) * N_NODES + bj + wj0 + lr * 4) = v;
        }
    }

    // ---- mirror tile (transpose), two 32-row halves
    if (ti != tj) {
        #pragma unroll
        for (int hh = 0; hh < 2; ++hh) {
            #pragma unroll
            for (int fi = 0; fi < 4; ++fi)
                #pragma unroll
                for (int fj = 2 * hh; fj < 2 * hh + 2; ++fj) {
                    int mrow = (fj - 2 * hh) * 16 + lr;        // 0..31
                    int chunk = (fi * 4 + g) ^ (mrow & 15);
                    *(f32x4*)(T + mrow * 64 + chunk * 4) = acc[fi][fj];
                }
            #pragma unroll
            for (int it = 0; it < 8; ++it) {
                int r = it * 4 + g;
                f32x4 v = *(const f32x4*)(T + r * 64 + ((lr ^ (r & 15)) << 2));
                *(f32x4*)(C + (size_t)(bj + wj0 + 32 * hh + r) * N_NODES + bi + wi0 + lr * 4) = v;
            }
        }
    }
}

extern "C" void kernel_launch(void* const* d_in, const int* in_sizes, int n_in,
                              void* d_out, int out_size, void* d_ws, size_t ws_size,
                              hipStream_t stream)
{
    const float* x   = (const float*)d_in[0];
    const int*   ei  = (const int*)d_in[1];
    const float* W1  = (const float*)d_in[2];
    const float* a1s = (const float*)d_in[3];
    const float* a1d = (const float*)d_in[4];
    const float* b1  = (const float*)d_in[5];
    const float* W2  = (const float*)d_in[6];
    const float* a2s = (const float*)d_in[7];
    const float* a2d = (const float*)d_in[8];
    const float* b2  = (const float*)d_in[9];
    float* C = (float*)d_out;

    // workspace layout (~15 MB)
    char* base = (char*)d_ws;
    float* h    = (float*)base;                          // 4 MB
    float* act  = (float*)(base + (4u  << 20));          // 4 MB
    int*   csr  = (int*)  (base + (8u  << 20));          // 4 MB (8192 x 128)
    int*   cnt  = (int*)  (base + (12u << 20));          // 32 KB
    float* asrc = (float*)(base + (12u << 20) + (64u << 10));
    float* adst = (float*)(base + (12u << 20) + (96u << 10));
    int*   bar  = (int*)  (base + (12u << 20) + (128u << 10));  // 8 ints
    unsigned short* hi = (unsigned short*)(base + (13u << 20)); // 2 MB

    // zero barrier counters + cnt, then ONE persistent kernel for the GAT
    // pipeline (manual grid barriers), then the AA^T GEMM.
    zero_k<<<8, 1024, 0, stream>>>(cnt, bar);

    MegaArgs A{ x, ei, W1, a1s, a1d, b1, W2, a2s, a2d, b2,
                h, act, cnt, csr, asrc, adst, hi, bar };
    gat_mega_k<<<GRID, 256, 0, stream>>>(A);

    // pred = act2 @ act2^T (hh-only): strict-lower pairs first, diagonals last
    aat_mfma_k<<<64 * 65 / 2, 256, 0, stream>>>(hi, C);
}

// Round 20
// 503.899 us; speedup vs baseline: 1.0877x; 1.0877x over previous
//
#include <hip/hip_runtime.h>
#include <cstddef>
#include <cstdint>

constexpr int N_NODES = 8192;
constexpr int E_EDGES = 262144;
constexpr int ET = E_EDGES + N_NODES;   // + self loops
constexpr int IN_DIM = 256;
constexpr int HID = 128;
constexpr int SLOTS = 128;              // per-dst bucket capacity (deg~Poisson(33))
constexpr int GRID = 512;               // 2 blocks/CU x 256 CUs -> all co-resident
constexpr float NEG_ATT = 0.2f;
constexpr float NEG_ACT = 0.02f;

typedef __attribute__((ext_vector_type(8))) short bf16x8;
typedef __attribute__((ext_vector_type(4))) float f32x4;

__device__ inline float lrelu(float v, float s) { return v >= 0.f ? v : s * v; }

#define GLD_LDS16(gaddr, laddr) \
    __builtin_amdgcn_global_load_lds( \
        (const __attribute__((address_space(1))) void*)(gaddr), \
        (__attribute__((address_space(3))) void*)(laddr), 16, 0, 0)

// ---- grid barrier, load-polling (round-19's atomicAdd-poll RMW ping-pong fix):
// arrive = one fetch_add per block; last arriver stores a release flag;
// everyone else polls the flag with device-scope LOADS (no line invalidation).
__device__ inline void grid_barrier(int* arrive, int* release, int nblk) {
    __threadfence();                 // release: prior global writes visible
    __syncthreads();
    if (threadIdx.x == 0) {
        int v = __hip_atomic_fetch_add(arrive, 1, __ATOMIC_ACQ_REL,
                                       __HIP_MEMORY_SCOPE_AGENT);
        if (v == nblk - 1) {
            __hip_atomic_store(release, 1, __ATOMIC_RELEASE,
                               __HIP_MEMORY_SCOPE_AGENT);
        } else {
            int spins = 0;
            while (__hip_atomic_load(release, __ATOMIC_ACQUIRE,
                                     __HIP_MEMORY_SCOPE_AGENT) == 0
                   && spins < (1 << 17)) {      // bounded: fail visibly, not hang
                __builtin_amdgcn_s_sleep(8);    // ~512 clk backoff between polls
                ++spins;
            }
        }
    }
    __syncthreads();
    __threadfence();                 // acquire side
}

__global__ __launch_bounds__(1024) void zero_k(int* __restrict__ cnt,
                                               int* __restrict__ bar) {
    int i = blockIdx.x * 1024 + threadIdx.x;
    if (i < N_NODES) cnt[i] = 0;
    if (i < 8) bar[i] = 0;           // 3 arrive counters + 3 release flags
}

struct MegaArgs {
    const float* x; const int* ei;
    const float* W1; const float* a1s; const float* a1d; const float* b1;
    const float* W2; const float* a2s; const float* a2d; const float* b2;
    float* h; float* act; int* cnt; int* csr;
    float* asrc; float* adst; unsigned short* hi; int* bar;
};

// ---- linear unit: 8 nodes, 256 threads (two 128-thread halves x 4 nodes) ----
__device__ void linear_unit(const float* __restrict__ x, const float* __restrict__ W,
                            const float* __restrict__ a_s, const float* __restrict__ a_d,
                            float* __restrict__ h, float* __restrict__ asrc,
                            float* __restrict__ adst, int in_dim,
                            float (*xs)[256], float (*red)[4][2], int t, int u)
{
    const int n0 = u * 8;
    const int c = t & 127, hb = t >> 7, w = t >> 6, lane = t & 63;
    for (int n = 0; n < 8; ++n)
        for (int i = t; i < in_dim; i += 256) xs[n][i] = x[(size_t)(n0 + n) * in_dim + i];
    __syncthreads();
    float acc[4] = {0.f, 0.f, 0.f, 0.f};
    const float* Wc = W + c;
    for (int i4 = 0; i4 < in_dim / 4; ++i4) {
        float4 xv[4];
        #pragma unroll
        for (int n = 0; n < 4; ++n) xv[n] = *(const float4*)&xs[hb * 4 + n][i4 * 4];
        float w0 = Wc[(i4 * 4 + 0) * HID];
        float w1 = Wc[(i4 * 4 + 1) * HID];
        float w2 = Wc[(i4 * 4 + 2) * HID];
        float w3 = Wc[(i4 * 4 + 3) * HID];
        #pragma unroll
        for (int n = 0; n < 4; ++n) {
            acc[n] = fmaf(xv[n].x, w0, acc[n]);
            acc[n] = fmaf(xv[n].y, w1, acc[n]);
            acc[n] = fmaf(xv[n].z, w2, acc[n]);
            acc[n] = fmaf(xv[n].w, w3, acc[n]);
        }
    }
    #pragma unroll
    for (int n = 0; n < 4; ++n) h[(size_t)(n0 + hb * 4 + n) * HID + c] = acc[n];
    const float As = a_s[c], Ad = a_d[c];
    #pragma unroll
    for (int n = 0; n < 4; ++n) {
        float vs = acc[n] * As, vd = acc[n] * Ad;
        #pragma unroll
        for (int off = 32; off; off >>= 1) {
            vs += __shfl_down(vs, off, 64);
            vd += __shfl_down(vd, off, 64);
        }
        if (lane == 0) { red[w][n][0] = vs; red[w][n][1] = vd; }
    }
    __syncthreads();
    if (t < 8) {
        int hb2 = t >> 2, n = t & 3;
        asrc[n0 + hb2 * 4 + n] = red[hb2 * 2][n][0] + red[hb2 * 2 + 1][n][0];
        adst[n0 + hb2 * 4 + n] = red[hb2 * 2][n][1] + red[hb2 * 2 + 1][n][1];
    }
    __syncthreads();   // xs/red reuse safety across grid-stride iterations
}

// ---- aggregate: one wave per dst (round-16 math verbatim) ----
template<int EMIT>
__device__ void agg_unit(int d, const int* __restrict__ cnt, const int* __restrict__ csr,
                         const float* __restrict__ asrc, const float* __restrict__ adst,
                         const float* __restrict__ h, const float* __restrict__ bias,
                         float* __restrict__ out, unsigned short* __restrict__ hi,
                         float* wbuf, int* sbuf, int lane)
{
    int deg = cnt[d]; if (deg > SLOTS) deg = SLOTS;
    const float ad = adst[d];
    const int base = d * SLOTS;

    float sm = 0.f;
    for (int j = lane; j < deg; j += 64) {
        int s = csr[base + j];
        float e = asrc[s] + ad; e = e >= 0.f ? e : NEG_ATT * e;
        float ww = __expf(e);
        wbuf[j] = ww; sbuf[j] = s;
        sm += ww;
    }
    #pragma unroll
    for (int off = 32; off; off >>= 1) sm += __shfl_xor(sm, off, 64);
    const float inv = 1.f / sm;

    float ax = 0.f, ay = 0.f;
    #pragma unroll 4
    for (int j = 0; j < deg; ++j) {
        float ww = wbuf[j];
        int   s  = sbuf[j];
        const float2 hv = *(const float2*)(h + ((size_t)s << 7) + lane * 2);
        ax = fmaf(ww, hv.x, ax);
        ay = fmaf(ww, hv.y, ay);
    }
    const float2 bv = *(const float2*)(bias + lane * 2);
    float vx = lrelu(fmaf(ax, inv, bv.x), NEG_ACT);
    float vy = lrelu(fmaf(ay, inv, bv.y), NEG_ACT);

    if (EMIT) {
        uint32_t ux = __float_as_uint(vx);
        uint32_t rhx = (ux + 0x7FFFu + ((ux >> 16) & 1u)) & 0xFFFF0000u;   // RNE
        uint32_t uy = __float_as_uint(vy);
        uint32_t rhy = (uy + 0x7FFFu + ((uy >> 16) & 1u)) & 0xFFFF0000u;
        *(uint32_t*)(hi + ((size_t)d << 7) + lane * 2) = (rhx >> 16) | (rhy & 0xFFFF0000u);
    } else {
        *(float2*)(out + ((size_t)d << 7) + lane * 2) = make_float2(vx, vy);
    }
}

// ---- persistent mega kernel: {append+linear1} | agg1 | linear2 | agg2 ----
__global__ __launch_bounds__(256, 2) void gat_mega_k(MegaArgs A)
{
    __shared__ __align__(16) float xs[8][256];
    __shared__ float red[4][4][2];
    __shared__ float wbuf[4][SLOTS];
    __shared__ int   sbuf[4][SLOTS];

    const int t = threadIdx.x;
    const int bid = blockIdx.x;
    const int lane = t & 63, wv = t >> 6;

    // P1a: bucketed adjacency append (independent of linear1; cnt zeroed by zero_k)
    for (int i = bid * 256 + t; i < ET; i += GRID * 256) {
        int s, d;
        if (i < E_EDGES) { s = A.ei[i]; d = A.ei[E_EDGES + i]; }
        else             { s = i - E_EDGES; d = s; }
        int pos = atomicAdd(&A.cnt[d], 1);
        if (pos < SLOTS) A.csr[d * SLOTS + pos] = s;
    }
    // P1b: layer-1 linear + logits
    for (int u = bid; u < N_NODES / 8; u += GRID)
        linear_unit(A.x, A.W1, A.a1s, A.a1d, A.h, A.asrc, A.adst, IN_DIM, xs, red, t, u);
    grid_barrier(&A.bar[0], &A.bar[4], GRID);

    // P2: layer-1 aggregate -> act
    for (int d = bid * 4 + wv; d < N_NODES; d += GRID * 4)
        agg_unit<0>(d, A.cnt, A.csr, A.asrc, A.adst, A.h, A.b1, A.act, nullptr,
                    wbuf[wv], sbuf[wv], lane);
    grid_barrier(&A.bar[1], &A.bar[5], GRID);

    // P3: layer-2 linear + logits (h, asrc, adst overwritten)
    for (int u = bid; u < N_NODES / 8; u += GRID)
        linear_unit(A.act, A.W2, A.a2s, A.a2d, A.h, A.asrc, A.adst, HID, xs, red, t, u);
    grid_barrier(&A.bar[2], &A.bar[6], GRID);

    // P4: layer-2 aggregate -> bf16 hi
    for (int d = bid * 4 + wv; d < N_NODES; d += GRID * 4)
        agg_unit<1>(d, A.cnt, A.csr, A.asrc, A.adst, A.h, A.b2, nullptr, A.hi,
                    wbuf[wv], sbuf[wv], lane);
}

// ---------------- C = A A^T, hh-only bf16 MFMA, symmetric ----------------
// ROUND-16 VERBATIM: BK=64 2-panel staging, halved epilogue (8 KB/wave T),
// 32 KB LDS + __launch_bounds__(256,4) -> 4 blocks/CU.
__global__ __launch_bounds__(256, 4) void aat_mfma_k(
    const unsigned short* __restrict__ hi, float* __restrict__ C)
{
    __shared__ __align__(16) unsigned char smraw[32768];
    unsigned short* sm = (unsigned short*)smraw;   // 2 panels of 128x64 bf16 (32 KB)
    const int t = threadIdx.x;
    const int lane = t & 63, wv = t >> 6;

    int b = blockIdx.x;
    int ti, tj;
    if (b < 2016) {                      // strict lower: ti in [1,63], tj < ti
        ti = (int)((__builtin_sqrtf(8.f * b + 1.f) + 1.f) * 0.5f);
        while (ti * (ti - 1) / 2 > b) --ti;
        while ((ti + 1) * ti / 2 <= b) ++ti;
        tj = b - ti * (ti - 1) / 2;
    } else {                             // diagonal (half work) scheduled last
        ti = b - 2016; tj = ti;
    }
    const int bi = ti * 128, bj = tj * 128;

    const int wi0 = (wv >> 1) * 64, wj0 = (wv & 1) * 64;
    const int lr = lane & 15, g = lane >> 4;

    f32x4 acc[4][4] = {};

    const int gbase[2] = { bi, bj };

    for (int ks = 0; ks < 2; ++ks) {
        if (ks) __syncthreads();
        #pragma unroll
        for (int arr = 0; arr < 2; ++arr) {
            #pragma unroll
            for (int call = 0; call < 4; ++call) {
                int r0 = wv * 32 + call * 8;            // wave-uniform
                int r = r0 + (lane >> 3);
                int chunk = (lane & 7) ^ (r & 7);
                const unsigned short* gp = hi
                    + (size_t)(gbase[arr] + r) * HID + ks * 64 + chunk * 8;
                unsigned short* lp = sm + arr * 8192 + r0 * 64;  // uniform base
                GLD_LDS16(gp, lp);
            }
        }
        __syncthreads();   // drains vmcnt

        #pragma unroll
        for (int kw = 0; kw < 2; ++kw) {
            bf16x8 ah[4], bh[4];
            #pragma unroll
            for (int f = 0; f < 4; ++f) {
                int rA = wi0 + f * 16 + lr;
                int csA = (kw * 4 + g) ^ (rA & 7);
                ah[f] = *(const bf16x8*)(sm + 0 * 8192 + rA * 64 + csA * 8);
                int rB = wj0 + f * 16 + lr;
                int csB = (kw * 4 + g) ^ (rB & 7);
                bh[f] = *(const bf16x8*)(sm + 1 * 8192 + rB * 64 + csB * 8);
            }
            #pragma unroll
            for (int fi = 0; fi < 4; ++fi)
                #pragma unroll
                for (int fj = 0; fj < 4; ++fj)
                    acc[fi][fj] = __builtin_amdgcn_mfma_f32_16x16x32_bf16(ah[fi], bh[fj], acc[fi][fj], 0, 0, 0);
        }
    }

    __syncthreads();                       // panels dead for all waves
    float* T = (float*)smraw + wv * 2048;  // per-wave 32x64 f32 (8 KB), XOR swizzle

    // ---- direct tile, two 32-row halves
    #pragma unroll
    for (int hh = 0; hh < 2; ++hh) {
        #pragma unroll
        for (int fi = 2 * hh; fi < 2 * hh + 2; ++fi)
            #pragma unroll
            for (int fj = 0; fj < 4; ++fj)
                #pragma unroll
                for (int q = 0; q < 4; ++q) {
                    int row = fi * 16 + g * 4 + q - 32 * hh;   // 0..31
                    int chunk = (fj * 4 + (lr >> 2)) ^ (row & 15);
                    T[row * 64 + chunk * 4 + (lr & 3)] = acc[fi][fj][q];
                }
        #pragma unroll
        for (int it = 0; it < 8; ++it) {
            int row = it * 4 + g;
            f32x4 v = *(const f32x4*)(T + row * 64 + ((lr ^ (row & 15)) << 2));
            *(f32x4*)(C + (size_t)(bi + wi0 + 32 * hh + row) * N_NODES + bj + wj0 + lr * 4) = v;
        }
    }

    // ---- mirror tile (transpose), two 32-row halves
    if (ti != tj) {
        #pragma unroll
        for (int hh = 0; hh < 2; ++hh) {
            #pragma unroll
            for (int fi = 0; fi < 4; ++fi)
                #pragma unroll
                for (int fj = 2 * hh; fj < 2 * hh + 2; ++fj) {
                    int mrow = (fj - 2 * hh) * 16 + lr;        // 0..31
                    int chunk = (fi * 4 + g) ^ (mrow & 15);
                    *(f32x4*)(T + mrow * 64 + chunk * 4) = acc[fi][fj];
                }
            #pragma unroll
            for (int it = 0; it < 8; ++it) {
                int r = it * 4 + g;
                f32x4 v = *(const f32x4*)(T + r * 64 + ((lr ^ (r & 15)) << 2));
                *(f32x4*)(C + (size_t)(bj + wj0 + 32 * hh + r) * N_NODES + bi + wi0 + lr * 4) = v;
            }
        }
    }
}

extern "C" void kernel_launch(void* const* d_in, const int* in_sizes, int n_in,
                              void* d_out, int out_size, void* d_ws, size_t ws_size,
                              hipStream_t stream)
{
    const float* x   = (const float*)d_in[0];
    const int*   ei  = (const int*)d_in[1];
    const float* W1  = (const float*)d_in[2];
    const float* a1s = (const float*)d_in[3];
    const float* a1d = (const float*)d_in[4];
    const float* b1  = (const float*)d_in[5];
    const float* W2  = (const float*)d_in[6];
    const float* a2s = (const float*)d_in[7];
    const float* a2d = (const float*)d_in[8];
    const float* b2  = (const float*)d_in[9];
    float* C = (float*)d_out;

    // workspace layout (~15 MB)
    char* base = (char*)d_ws;
    float* h    = (float*)base;                          // 4 MB
    float* act  = (float*)(base + (4u  << 20));          // 4 MB
    int*   csr  = (int*)  (base + (8u  << 20));          // 4 MB (8192 x 128)
    int*   cnt  = (int*)  (base + (12u << 20));          // 32 KB
    float* asrc = (float*)(base + (12u << 20) + (64u << 10));
    float* adst = (float*)(base + (12u << 20) + (96u << 10));
    int*   bar  = (int*)  (base + (12u << 20) + (128u << 10));  // 8 ints
    unsigned short* hi = (unsigned short*)(base + (13u << 20)); // 2 MB

    // zero barrier counters + cnt, then ONE persistent kernel for the GAT
    // pipeline (3 load-polling grid barriers), then the AA^T GEMM.
    zero_k<<<8, 1024, 0, stream>>>(cnt, bar);

    MegaArgs A{ x, ei, W1, a1s, a1d, b1, W2, a2s, a2d, b2,
                h, act, cnt, csr, asrc, adst, hi, bar };
    gat_mega_k<<<GRID, 256, 0, stream>>>(A);

    // pred = act2 @ act2^T (hh-only): strict-lower pairs first, diagonals last
    aat_mfma_k<<<64 * 65 / 2, 256, 0, stream>>>(hi, C);
}

// Round 21
// 134.418 us; speedup vs baseline: 4.0774x; 3.7488x over previous
//
#include <hip/hip_runtime.h>
#include <cstddef>
#include <cstdint>

constexpr int N_NODES = 8192;
constexpr int E_EDGES = 262144;
constexpr int ET = E_EDGES + N_NODES;   // + self loops
constexpr int IN_DIM = 256;
constexpr int HID = 128;
constexpr int SLOTS = 128;              // per-dst bucket capacity (deg~Poisson(33))
constexpr float NEG_ATT = 0.2f;
constexpr float NEG_ACT = 0.02f;

typedef __attribute__((ext_vector_type(8))) short bf16x8;
typedef __attribute__((ext_vector_type(4))) float f32x4;

__device__ inline float lrelu(float v, float s) { return v >= 0.f ? v : s * v; }

#define GLD_LDS16(gaddr, laddr) \
    __builtin_amdgcn_global_load_lds( \
        (const __attribute__((address_space(1))) void*)(gaddr), \
        (__attribute__((address_space(3))) void*)(laddr), 16, 0, 0)

// ---------------- graph build: bucketed adjacency ----------------
__global__ void append_k(const int* __restrict__ ei, int* __restrict__ cnt,
                         int* __restrict__ csr) {
    int i = blockIdx.x * blockDim.x + threadIdx.x;
    if (i >= ET) return;
    int s, d;
    if (i < E_EDGES) { s = ei[i]; d = ei[E_EDGES + i]; }
    else             { s = i - E_EDGES; d = s; }
    int pos = atomicAdd(&cnt[d], 1);
    if (pos < SLOTS) csr[d * SLOTS + pos] = s;
}

// ---------------- h = x@W + attention logits (8 nodes / block) ----------------
// Layer-1 instance also zeroes cnt[] (blocks 0..63) for the subsequent append_k.
__global__ __launch_bounds__(128) void linear_alpha_k(
    const float* __restrict__ x, const float* __restrict__ W,
    const float* __restrict__ a_src, const float* __restrict__ a_dst,
    float* __restrict__ h, float* __restrict__ asrc, float* __restrict__ adst,
    int in_dim, int* __restrict__ cntz)
{
    __shared__ __align__(16) float xs[8][256];
    __shared__ float red[2][8][2];
    const int t = threadIdx.x;
    const int n0 = blockIdx.x * 8;
    if (cntz != nullptr && blockIdx.x < 64) cntz[blockIdx.x * 128 + t] = 0;
    for (int n = 0; n < 8; ++n)
        for (int i = t; i < in_dim; i += 128) xs[n][i] = x[(size_t)(n0 + n) * in_dim + i];
    __syncthreads();
    float acc[8] = {0.f,0.f,0.f,0.f,0.f,0.f,0.f,0.f};
    const float* Wc = W + t;
    for (int i4 = 0; i4 < in_dim / 4; ++i4) {
        float4 xv[8];
        #pragma unroll
        for (int n = 0; n < 8; ++n) xv[n] = *(const float4*)&xs[n][i4 * 4];
        float w0 = Wc[(i4 * 4 + 0) * HID];
        float w1 = Wc[(i4 * 4 + 1) * HID];
        float w2 = Wc[(i4 * 4 + 2) * HID];
        float w3 = Wc[(i4 * 4 + 3) * HID];
        #pragma unroll
        for (int n = 0; n < 8; ++n) {
            acc[n] = fmaf(xv[n].x, w0, acc[n]);
            acc[n] = fmaf(xv[n].y, w1, acc[n]);
            acc[n] = fmaf(xv[n].z, w2, acc[n]);
            acc[n] = fmaf(xv[n].w, w3, acc[n]);
        }
    }
    #pragma unroll
    for (int n = 0; n < 8; ++n) h[(size_t)(n0 + n) * HID + t] = acc[n];
    const float As = a_src[t], Ad = a_dst[t];
    const int wv_ = t >> 6;
    #pragma unroll
    for (int n = 0; n < 8; ++n) {
        float vs = acc[n] * As, vd = acc[n] * Ad;
        #pragma unroll
        for (int off = 32; off; off >>= 1) {
            vs += __shfl_down(vs, off, 64);
            vd += __shfl_down(vd, off, 64);
        }
        if ((t & 63) == 0) { red[wv_][n][0] = vs; red[wv_][n][1] = vd; }
    }
    __syncthreads();
    if (t < 8) {
        asrc[n0 + t] = red[0][t][0] + red[1][t][0];
        adst[n0 + t] = red[0][t][1] + red[1][t][1];
    }
}

// ------ fused softmax + aggregate + bias + leakyrelu: ONE WAVE PER DST --------
// EMIT=1 writes bf16 hi (RNE) only — the AA^T GEMM is hh-only.
template<int EMIT>
__global__ __launch_bounds__(256) void gat_agg_k(
    const int* __restrict__ cnt, const int* __restrict__ csr,
    const float* __restrict__ asrc, const float* __restrict__ adst,
    const float* __restrict__ h, const float* __restrict__ bias,
    float* __restrict__ out, unsigned short* __restrict__ hi)
{
    __shared__ float wbuf[4][SLOTS];
    __shared__ int   sbuf[4][SLOTS];
    const int wv = threadIdx.x >> 6, lane = threadIdx.x & 63;
    const int d = blockIdx.x * 4 + wv;
    int deg = cnt[d]; if (deg > SLOTS) deg = SLOTS;
    const float ad = adst[d];
    const int base = d * SLOTS;

    float sm = 0.f;
    for (int j = lane; j < deg; j += 64) {
        int s = csr[base + j];
        float e = asrc[s] + ad; e = e >= 0.f ? e : NEG_ATT * e;
        float ww = __expf(e);
        wbuf[wv][j] = ww; sbuf[wv][j] = s;
        sm += ww;
    }
    #pragma unroll
    for (int off = 32; off; off >>= 1) sm += __shfl_xor(sm, off, 64);
    const float inv = 1.f / sm;

    float ax = 0.f, ay = 0.f;
    #pragma unroll 4
    for (int j = 0; j < deg; ++j) {
        float ww = wbuf[wv][j];
        int   s  = sbuf[wv][j];
        const float2 hv = *(const float2*)(h + ((size_t)s << 7) + lane * 2);
        ax = fmaf(ww, hv.x, ax);
        ay = fmaf(ww, hv.y, ay);
    }
    const float2 bv = *(const float2*)(bias + lane * 2);
    float vx = lrelu(fmaf(ax, inv, bv.x), NEG_ACT);
    float vy = lrelu(fmaf(ay, inv, bv.y), NEG_ACT);

    if (EMIT) {
        uint32_t ux = __float_as_uint(vx);
        uint32_t rhx = (ux + 0x7FFFu + ((ux >> 16) & 1u)) & 0xFFFF0000u;   // RNE
        uint32_t uy = __float_as_uint(vy);
        uint32_t rhy = (uy + 0x7FFFu + ((uy >> 16) & 1u)) & 0xFFFF0000u;
        *(uint32_t*)(hi + ((size_t)d << 7) + lane * 2) = (rhx >> 16) | (rhy & 0xFFFF0000u);
    } else {
        *(float2*)(out + ((size_t)d << 7) + lane * 2) = make_float2(vx, vy);
    }
}

// ---------------- C = A A^T, hh-only bf16 MFMA, symmetric ----------------
// BK=64 2-panel global_load_lds staging (pre-swizzled source + linear LDS dest),
// halved epilogue bounce (8 KB/wave T) -> 32 KB LDS + launch_bounds(256,4)
// -> 4 blocks/CU; plain cached full-line stores; strict-lower pairs first,
// diagonals (half work) scheduled last.
__global__ __launch_bounds__(256, 4) void aat_mfma_k(
    const unsigned short* __restrict__ hi, float* __restrict__ C)
{
    __shared__ __align__(16) unsigned char smraw[32768];
    unsigned short* sm = (unsigned short*)smraw;   // 2 panels of 128x64 bf16 (32 KB)
    const int t = threadIdx.x;
    const int lane = t & 63, wv = t >> 6;

    int b = blockIdx.x;
    int ti, tj;
    if (b < 2016) {                      // strict lower: ti in [1,63], tj < ti
        ti = (int)((__builtin_sqrtf(8.f * b + 1.f) + 1.f) * 0.5f);
        while (ti * (ti - 1) / 2 > b) --ti;
        while ((ti + 1) * ti / 2 <= b) ++ti;
        tj = b - ti * (ti - 1) / 2;
    } else {                             // diagonal (half work) scheduled last
        ti = b - 2016; tj = ti;
    }
    const int bi = ti * 128, bj = tj * 128;

    const int wi0 = (wv >> 1) * 64, wj0 = (wv & 1) * 64;
    const int lr = lane & 15, g = lane >> 4;

    f32x4 acc[4][4] = {};

    const int gbase[2] = { bi, bj };

    for (int ks = 0; ks < 2; ++ks) {
        if (ks) __syncthreads();
        #pragma unroll
        for (int arr = 0; arr < 2; ++arr) {
            #pragma unroll
            for (int call = 0; call < 4; ++call) {
                int r0 = wv * 32 + call * 8;            // wave-uniform
                int r = r0 + (lane >> 3);
                int chunk = (lane & 7) ^ (r & 7);
                const unsigned short* gp = hi
                    + (size_t)(gbase[arr] + r) * HID + ks * 64 + chunk * 8;
                unsigned short* lp = sm + arr * 8192 + r0 * 64;  // uniform base
                GLD_LDS16(gp, lp);
            }
        }
        __syncthreads();   // drains vmcnt

        #pragma unroll
        for (int kw = 0; kw < 2; ++kw) {
            bf16x8 ah[4], bh[4];
            #pragma unroll
            for (int f = 0; f < 4; ++f) {
                int rA = wi0 + f * 16 + lr;
                int csA = (kw * 4 + g) ^ (rA & 7);
                ah[f] = *(const bf16x8*)(sm + 0 * 8192 + rA * 64 + csA * 8);
                int rB = wj0 + f * 16 + lr;
                int csB = (kw * 4 + g) ^ (rB & 7);
                bh[f] = *(const bf16x8*)(sm + 1 * 8192 + rB * 64 + csB * 8);
            }
            #pragma unroll
            for (int fi = 0; fi < 4; ++fi)
                #pragma unroll
                for (int fj = 0; fj < 4; ++fj)
                    acc[fi][fj] = __builtin_amdgcn_mfma_f32_16x16x32_bf16(ah[fi], bh[fj], acc[fi][fj], 0, 0, 0);
        }
    }

    __syncthreads();                       // panels dead for all waves
    float* T = (float*)smraw + wv * 2048;  // per-wave 32x64 f32 (8 KB), XOR swizzle

    // ---- direct tile, two 32-row halves
    #pragma unroll
    for (int hh = 0; hh < 2; ++hh) {
        #pragma unroll
        for (int fi = 2 * hh; fi < 2 * hh + 2; ++fi)
            #pragma unroll
            for (int fj = 0; fj < 4; ++fj)
                #pragma unroll
                for (int q = 0; q < 4; ++q) {
                    int row = fi * 16 + g * 4 + q - 32 * hh;   // 0..31
                    int chunk = (fj * 4 + (lr >> 2)) ^ (row & 15);
                    T[row * 64 + chunk * 4 + (lr & 3)] = acc[fi][fj][q];
                }
        #pragma unroll
        for (int it = 0; it < 8; ++it) {
            int row = it * 4 + g;
            f32x4 v = *(const f32x4*)(T + row * 64 + ((lr ^ (row & 15)) << 2));
            *(f32x4*)(C + (size_t)(bi + wi0 + 32 * hh + row) * N_NODES + bj + wj0 + lr * 4) = v;
        }
    }

    // ---- mirror tile (transpose), two 32-row halves
    if (ti != tj) {
        #pragma unroll
        for (int hh = 0; hh < 2; ++hh) {
            #pragma unroll
            for (int fi = 0; fi < 4; ++fi)
                #pragma unroll
                for (int fj = 2 * hh; fj < 2 * hh + 2; ++fj) {
                    int mrow = (fj - 2 * hh) * 16 + lr;        // 0..31
                    int chunk = (fi * 4 + g) ^ (mrow & 15);
                    *(f32x4*)(T + mrow * 64 + chunk * 4) = acc[fi][fj];
                }
            #pragma unroll
            for (int it = 0; it < 8; ++it) {
                int r = it * 4 + g;
                f32x4 v = *(const f32x4*)(T + r * 64 + ((lr ^ (r & 15)) << 2));
                *(f32x4*)(C + (size_t)(bj + wj0 + 32 * hh + r) * N_NODES + bi + wi0 + lr * 4) = v;
            }
        }
    }
}

extern "C" void kernel_launch(void* const* d_in, const int* in_sizes, int n_in,
                              void* d_out, int out_size, void* d_ws, size_t ws_size,
                              hipStream_t stream)
{
    const float* x   = (const float*)d_in[0];
    const int*   ei  = (const int*)d_in[1];
    const float* W1  = (const float*)d_in[2];
    const float* a1s = (const float*)d_in[3];
    const float* a1d = (const float*)d_in[4];
    const float* b1  = (const float*)d_in[5];
    const float* W2  = (const float*)d_in[6];
    const float* a2s = (const float*)d_in[7];
    const float* a2d = (const float*)d_in[8];
    const float* b2  = (const float*)d_in[9];
    float* C = (float*)d_out;

    // workspace layout (~15 MB)
    char* base = (char*)d_ws;
    float* h    = (float*)base;                          // 4 MB
    float* act  = (float*)(base + (4u  << 20));          // 4 MB
    int*   csr  = (int*)  (base + (8u  << 20));          // 4 MB (8192 x 128)
    int*   cnt  = (int*)  (base + (12u << 20));          // 32 KB
    float* asrc = (float*)(base + (12u << 20) + (64u << 10));
    float* adst = (float*)(base + (12u << 20) + (96u << 10));
    unsigned short* hi = (unsigned short*)(base + (13u << 20)); // 2 MB

    const int eb = (ET + 255) / 256;

    // layer 1 linear (also zeroes cnt), then adjacency build, then aggregate
    linear_alpha_k<<<N_NODES / 8, 128, 0, stream>>>(x, W1, a1s, a1d, h, asrc, adst, IN_DIM, cnt);
    append_k<<<eb, 256, 0, stream>>>(ei, cnt, csr);
    gat_agg_k<0><<<N_NODES / 4, 256, 0, stream>>>(cnt, csr, asrc, adst, h, b1, act, nullptr);
    // layer 2 (emits bf16 hi directly)
    linear_alpha_k<<<N_NODES / 8, 128, 0, stream>>>(act, W2, a2s, a2d, h, asrc, adst, HID, nullptr);
    gat_agg_k<1><<<N_NODES / 4, 256, 0, stream>>>(cnt, csr, asrc, adst, h, b2, nullptr, hi);

    // pred = act2 @ act2^T (hh-only): strict-lower pairs first, diagonals last
    aat_mfma_k<<<64 * 65 / 2, 256, 0, stream>>>(hi, C);
}